// Round 9
// baseline (395.095 us; speedup 1.0000x reference)
//
#include <hip/hip_runtime.h>
#include <hip/hip_bf16.h>

// Flash attention fwd. q[B,N,D], k[B,D,N] (=K^T), v[B,N,D] fp32 in, fp32 out.
// B=16, N=2048, D=128. fp16 MFMA (32x32x16), fp32 accumulate.
// R9: R8 skeleton at BM=64 / 256-thr blocks -> grid 512 = 2 blocks/CU =
// 16 waves/CU (2 consumer + 2 producer waves per SIMD, from independent
// blocks). Attacks the latency-bound regime diagnosed in R8 (all pipes
// <35%, time invariant across R5-R8 structures at ~1 compute wave/SIMD).
//  - Waves 0-1: consumers, 32 q-rows each. Waves 2-3: producers,
//    double-buffered K/V staging (BN=32/iter). One barrier per iter.
//  - 32x32x16 MFMA, transposed convention (S^T = K'xQ^T, O^T = V'xP^T);
//    softmax per-lane (q=lane&31, 1 shfl_xor); P^T roundtrip 4 b64 writes
//    + 2 b128 reads, PK=40 pad.
//  - C/D layout (m74/m101): col=lane&31, row=(reg&3)+8*(reg>>2)+4*(lane>>5).
//    A: [m=lane&31][k=(lane>>5)*8+j]; B: [k=(lane>>5)*8+j][n=lane&31].
//  - K/V LDS transposed w/ XOR swizzle (<=2-way banks). XCD swizzle: 2
//    batches/XCD -> K/V working set ~4MB = per-XCD L2 (R5: FETCH 139->25MB).

typedef __attribute__((ext_vector_type(8))) _Float16 f16x8;
typedef __attribute__((ext_vector_type(16))) float f32x16;

constexpr int Bz = 16;
constexpr int Nn = 2048;
constexpr int Dd = 128;
constexpr int BM = 64;   // q rows per block (2 consumer waves x 32)
constexpr int BN = 32;   // keys per iteration
constexpr int PK = 40;   // P^T row stride (ushorts), 32 + 8 pad

__device__ __forceinline__ int swz(int r) { return (r ^ (r >> 3)) & 7; }
__device__ __forceinline__ int sw4(int d) { return ((d >> 1) ^ (d >> 3)) & 3; }

__device__ __forceinline__ uint packh2(float a, float b) {
    union { _Float16 h[2]; uint u; } p;
    p.h[0] = (_Float16)a; p.h[1] = (_Float16)b;
    return p.u;
}

__global__ __launch_bounds__(256, 4)
void fattn_kernel(const float* __restrict__ qg,
                  const float* __restrict__ kg,
                  const float* __restrict__ vg,
                  float* __restrict__ og)
{
    __shared__ ushort lds_k[2][BN * Dd];   // [kk][d-pair ^ swz]   2 x 8 KB
    __shared__ ushort lds_v[2][Dd * BN];   // [d][kk-pair ^ sw4]   2 x 8 KB
    __shared__ ushort lds_p[2][32 * PK];   // per-consumer-wave P^T [q][kk] 5 KB

    const int bid  = blockIdx.x;           // 512 blocks
    const int xcd  = bid & 7;
    const int idx  = bid >> 3;             // 0..63
    const int b    = xcd * 2 + (idx >> 5);
    const int q0   = (idx & 31) * BM;
    const int tid  = threadIdx.x;
    const int wv   = tid >> 6;             // 0..3
    const int lane = tid & 63;
    const int h    = lane >> 5;            // half-wave (k-slice)
    const int l31  = lane & 31;
    const bool producer = (wv >= 2);

    // ================= producer state =================
    const int ptid = (wv - 2) * 64 + lane;     // 0..127 (producers only)
    const int kgrp = ptid & 3;     // K: n-group (8 n's)
    const int krow = ptid >> 2;    // K: d-pair 0..31 (+32*pass)
    const int vgrp = ptid & 15;    // V: d-group (8 d's)
    const int vrow = ptid >> 4;    // V: kk-pair 0..7 (+8*pass)
    const float* kbase = kg + (size_t)b * Dd * Nn;
    const float* vbase = vg + (size_t)b * Nn * Dd;
    float4 kr[8], vr[8];

    auto issue_loads = [&](int n0) {
        #pragma unroll
        for (int pass = 0; pass < 2; ++pass) {
            const int d0 = (krow + pass * 32) * 2;
            const float* s0 = kbase + (size_t)d0 * Nn + n0 + kgrp * 8;
            kr[pass * 4 + 0] = ((const float4*)s0)[0];
            kr[pass * 4 + 1] = ((const float4*)s0)[1];
            kr[pass * 4 + 2] = ((const float4*)(s0 + Nn))[0];
            kr[pass * 4 + 3] = ((const float4*)(s0 + Nn))[1];
            const int kk0 = (vrow + pass * 8) * 2;
            const float* t0 = vbase + (size_t)(n0 + kk0) * Dd + vgrp * 8;
            vr[pass * 4 + 0] = ((const float4*)t0)[0];
            vr[pass * 4 + 1] = ((const float4*)t0)[1];
            vr[pass * 4 + 2] = ((const float4*)(t0 + Dd))[0];
            vr[pass * 4 + 3] = ((const float4*)(t0 + Dd))[1];
        }
    };
    auto write_lds = [&](int buf) {
        uint* kw = (uint*)lds_k[buf];
        uint* vw = (uint*)lds_v[buf];
        #pragma unroll
        for (int pass = 0; pass < 2; ++pass) {
            const int dp = krow + pass * 32;          // d-pair 0..63
            const float* av = (const float*)&kr[pass * 4 + 0];  // K row 2dp
            const float* bv = (const float*)&kr[pass * 4 + 2];  // K row 2dp+1
            #pragma unroll
            for (int j = 0; j < 8; ++j) {
                const int n = kgrp * 8 + j;
                kw[n * (Dd / 2) + (dp ^ (swz(n) << 2))] = packh2(av[j], bv[j]);
            }
            const int kp = vrow + pass * 8;           // kk-pair 0..15
            const float* cv = (const float*)&vr[pass * 4 + 0];  // V row 2kp
            const float* dv = (const float*)&vr[pass * 4 + 2];  // V row 2kp+1
            #pragma unroll
            for (int j = 0; j < 8; ++j) {
                const int dd = vgrp * 8 + j;
                vw[dd * (BN / 2) + (kp ^ (sw4(dd) << 2))] = packh2(cv[j], dv[j]);
            }
        }
    };

    // ================= consumer state =================
    // Q^T as B-operand: lane holds Q[q = q0+wv*32+l31][d = c*16 + h*8 + j]
    f16x8 qf[8];
    if (!producer) {
        const float* qp = qg + (size_t)(b * Nn + q0 + wv * 32 + l31) * Dd + h * 8;
        #pragma unroll
        for (int c = 0; c < 8; ++c) {
            float4 x0 = *(const float4*)(qp + c * 16);
            float4 x1 = *(const float4*)(qp + c * 16 + 4);
            const float xv[8] = {x0.x, x0.y, x0.z, x0.w, x1.x, x1.y, x1.z, x1.w};
            union { f16x8 v; _Float16 e[8]; } u;
            #pragma unroll
            for (int j = 0; j < 8; ++j) u.e[j] = (_Float16)xv[j];
            qf[c] = u.v;
        }
    }
    f32x16 accO[4];   // O^T[dout = dt*32 + C-row][q = l31]
    #pragma unroll
    for (int dt = 0; dt < 4; ++dt)
        #pragma unroll
        for (int r = 0; r < 16; ++r) accO[dt][r] = 0.f;
    float m_i = -1e30f, l_i = 0.f;   // per-lane (q = l31; halves merged via shfl)

    // ================= pipeline =================
    if (producer) {
        issue_loads(0);
        write_lds(0);
    }
    __syncthreads();

    constexpr int ITERS = Nn / BN;   // 64
    for (int it = 0; it < ITERS; ++it) {
        const int cur = it & 1;
        if (producer) {
            if (it + 1 < ITERS) {
                issue_loads((it + 1) * BN);
                write_lds(cur ^ 1);
            }
        } else {
            const ushort* kb = lds_k[cur];
            const ushort* vb = lds_v[cur];

            // ---- S^T[kk=32][q=32] = K' x Q^T, K-dim 128 in 8 chunks ----
            f32x16 accS;
            #pragma unroll
            for (int r = 0; r < 16; ++r) accS[r] = 0.f;
            {
                const int kkrow = l31;
                const int sw = swz(kkrow) << 3;
                #pragma unroll
                for (int c = 0; c < 8; ++c) {
                    f16x8 kf = *(const f16x8*)&kb[kkrow * Dd + ((c * 16 + h * 8) ^ sw)];
                    accS = __builtin_amdgcn_mfma_f32_32x32x16_f16(kf, qf[c], accS, 0, 0, 0);
                }
            }

            // ---- online softmax, per-lane row (q = l31) ----
            float mx = accS[0];
            #pragma unroll
            for (int r = 1; r < 16; ++r) mx = fmaxf(mx, accS[r]);
            mx = fmaxf(mx, __shfl_xor(mx, 32, 64));
            const float mn = fmaxf(m_i, mx);
            const float alpha = __expf(m_i - mn);
            m_i = mn;
            float local = 0.f;
            #pragma unroll
            for (int r = 0; r < 16; ++r) {
                const float p = __expf(accS[r] - mn);
                accS[r] = p;
                local += p;
            }
            l_i = l_i * alpha + local;
            #pragma unroll
            for (int dt = 0; dt < 4; ++dt)
                #pragma unroll
                for (int r = 0; r < 16; ++r) accO[dt][r] *= alpha;

            // ---- P^T -> LDS [q][kk] (wave-private); C rows = 8g+4h+(0..3) ----
            ushort* pl = lds_p[wv];
            #pragma unroll
            for (int g = 0; g < 4; ++g) {
                uint2 w;
                w.x = packh2(accS[4 * g + 0], accS[4 * g + 1]);
                w.y = packh2(accS[4 * g + 2], accS[4 * g + 3]);
                *(uint2*)(pl + l31 * PK + 8 * g + 4 * h) = w;   // ds_write_b64
            }
            // B-frags: chunk c' of 16 kk: [q][16c' + 8h .. +8]
            f16x8 pf0 = *(const f16x8*)&pl[l31 * PK + 8 * h];
            f16x8 pf1 = *(const f16x8*)&pl[l31 * PK + 16 + 8 * h];

            // ---- O^T += V' x P^T : 4 dout tiles x 2 kk-chunks ----
            #pragma unroll
            for (int dt = 0; dt < 4; ++dt) {
                const int drow = dt * 32 + l31;
                const int sv = sw4(drow) << 3;
                f16x8 vf0 = *(const f16x8*)&vb[drow * BN + ((8 * h) ^ sv)];
                f16x8 vf1 = *(const f16x8*)&vb[drow * BN + ((16 + 8 * h) ^ sv)];
                accO[dt] = __builtin_amdgcn_mfma_f32_32x32x16_f16(vf0, pf0, accO[dt], 0, 0, 0);
                accO[dt] = __builtin_amdgcn_mfma_f32_32x32x16_f16(vf1, pf1, accO[dt], 0, 0, 0);
            }
        }
        __syncthreads();
    }

    // ================= epilogue (consumers) =================
    if (!producer) {
        float l = l_i + __shfl_xor(l_i, 32, 64);
        const float inv = 1.f / l;
        float* ob = og + (size_t)(b * Nn + q0 + wv * 32 + l31) * Dd;
        #pragma unroll
        for (int dt = 0; dt < 4; ++dt) {
            #pragma unroll
            for (int g = 0; g < 4; ++g) {
                float4 val;
                val.x = accO[dt][4 * g + 0] * inv;
                val.y = accO[dt][4 * g + 1] * inv;
                val.z = accO[dt][4 * g + 2] * inv;
                val.w = accO[dt][4 * g + 3] * inv;
                *(float4*)(ob + dt * 32 + 8 * g + 4 * h) = val;
            }
        }
    }
}

extern "C" void kernel_launch(void* const* d_in, const int* in_sizes, int n_in,
                              void* d_out, int out_size, void* d_ws, size_t ws_size,
                              hipStream_t stream) {
    const float* q = (const float*)d_in[0];
    const float* k = (const float*)d_in[1];
    const float* v = (const float*)d_in[2];
    float* o = (float*)d_out;
    (void)d_ws; (void)ws_size; (void)in_sizes; (void)n_in; (void)out_size;
    fattn_kernel<<<dim3(Bz * (Nn / BM)), dim3(256), 0, stream>>>(q, k, v, o);
}

// Round 10
// 172.304 us; speedup vs baseline: 2.2930x; 2.2930x over previous
//
#include <hip/hip_runtime.h>
#include <hip/hip_bf16.h>

// Flash attention fwd. q[B,N,D], k[B,D,N] (=K^T), v[B,N,D] fp32 in, fp32 out.
// B=16, N=2048, D=128. fp16 MFMA 16x16x32, fp32 accumulate.
// R10: in-block K-split to break the 8-waves/CU plateau.
//  - Block 512 thr = 8 waves, BM=64 (4 q-strips of 16 rows). Waves 0-3:
//    strips 0-3 over keys [0,1024); waves 4-7: same strips over [1024,2048).
//    Grid 512 = 2 blocks/CU = 16 waves/CU = 4 waves/SIMD (2 independent
//    compute streams/SIMD -- the latency fix R9 failed to deliver).
//  - Exact online-softmax merge of the two halves in-block via LDS overlay.
//  - No register prefetch (R9 spill lesson): stage->barrier->compute->barrier,
//    TLP hides L2-hit latency. launch_bounds(512,4) caps VGPR at 128;
//    per-wave state ~95 regs -> no spill.
//  - Transposed convention (R7): GEMM1 S^T=K'xQ^T (softmax per-lane q=l15,
//    2 shfl_xor); GEMM2 O^T=V'xP^T (P roundtrip 2 b64 writes + 1 b128 read).
//  - K/V LDS XOR-swizzled (<=2-way banks); XCD swizzle keeps K/V in per-XCD L2.
// MFMA 16x16x32 layouts (verified m89/m91 + R3-R8 end-to-end):
//   A: lane holds A[m=l15][k=quad*8+j]; B: B[k=quad*8+j][n=l15];
//   C/D: lane reg r holds C[row=quad*4+r][col=l15]

typedef __attribute__((ext_vector_type(8))) _Float16 f16x8;
typedef __attribute__((ext_vector_type(4))) float f32x4;

constexpr int Bz = 16;
constexpr int Nn = 2048;
constexpr int Dd = 128;
constexpr int BM = 64;        // q rows per block (4 strips x 16)
constexpr int BN = 32;        // keys per iteration per half
constexpr int HALF = Nn / 2;  // 1024
constexpr int ITERS = HALF / BN;  // 32
constexpr int PK = 40;        // P^T row stride (ushorts)

__device__ __forceinline__ int swz(int r) { return (r ^ (r >> 3)) & 7; }
__device__ __forceinline__ int sw4(int d) { return ((d >> 1) ^ (d >> 3)) & 3; }

__device__ __forceinline__ uint packh2(float a, float b) {
    union { _Float16 h[2]; uint u; } p;
    p.h[0] = (_Float16)a; p.h[1] = (_Float16)b;
    return p.u;
}

__global__ __launch_bounds__(512, 4)
void fattn_kernel(const float* __restrict__ qg,
                  const float* __restrict__ kg,
                  const float* __restrict__ vg,
                  float* __restrict__ og)
{
    // 43008 B total. ushort offsets:
    //   kbuf[g] @ g*4096      : K tile [kk=32][d=128], g = key-half
    //   vbuf[g] @ 8192+g*4096 : V tile [d=128][kk=32]
    //   pbuf[w] @ 16384+wv*640: per-wave P^T [q=16][PK]
    // epilogue overlay: floats[0,8192) = merge O buffer (4 strips x 16 x 128);
    //                   floats @ushort16384 = ml[4][16][2]
    __shared__ ushort smem[21504];

    const int bid  = blockIdx.x;           // 512 blocks
    const int xcd  = bid & 7;
    const int idx  = bid >> 3;             // 0..63
    const int b    = xcd * 2 + (idx >> 5);
    const int q0   = (idx & 31) * BM;
    const int tid  = threadIdx.x;
    const int wv   = tid >> 6;             // 0..7
    const int lane = tid & 63;
    const int quad = lane >> 4;
    const int l15  = lane & 15;
    const int w    = wv & 3;               // q-strip
    const int g    = wv >> 2;              // key-half group

    ushort* const kb = smem + g * 4096;
    ushort* const vb = smem + 8192 + g * 4096;
    ushort* const pl = smem + 16384 + wv * 640;
    uint* const kw = (uint*)kb;
    uint* const vw = (uint*)vb;

    // staging mapping: each group's 256 threads stage its own K/V tile
    const int gtid = tid & 255;
    const int kgN = (gtid & 3) * 8;        // K: base n (8 n's)
    const int kdp = gtid >> 2;             // K: d-pair 0..63
    const int vgD = (gtid & 15) * 8;       // V: base d (8 d's)
    const int vkp = gtid >> 4;             // V: kk-pair 0..15
    const float* kbase = kg + (size_t)b * Dd * Nn;
    const float* vbase = vg + (size_t)b * Nn * Dd;

    // ---- Q fragments (B operand), fp32 -> fp16, in registers ----
    f16x8 qf[4];
    {
        const float* qp = qg + (size_t)(b * Nn + q0 + w * 16 + l15) * Dd + quad * 8;
        #pragma unroll
        for (int c = 0; c < 4; ++c) {
            float4 x0 = *(const float4*)(qp + c * 32);
            float4 x1 = *(const float4*)(qp + c * 32 + 4);
            const float xv[8] = {x0.x, x0.y, x0.z, x0.w, x1.x, x1.y, x1.z, x1.w};
            union { f16x8 v; _Float16 e[8]; } u;
            #pragma unroll
            for (int j = 0; j < 8; ++j) u.e[j] = (_Float16)xv[j];
            qf[c] = u.v;
        }
    }
    f32x4 accO[8];   // O^T[dout=dt*16+quad*4+r][q=l15], unnormalized
    #pragma unroll
    for (int i = 0; i < 8; ++i) accO[i] = f32x4{0.f, 0.f, 0.f, 0.f};
    float m_i = -1e30f, l_i = 0.f;   // per-lane; l is quad-partial

    for (int it = 0; it < ITERS; ++it) {
        const int n0 = g * HALF + it * BN;
        // ---- stage K tile: fp32 [d][n] -> kb[kk][d-pair ^ swz] ----
        {
            const float* s0 = kbase + (size_t)(2 * kdp) * Nn + n0 + kgN;
            float4 a0 = ((const float4*)s0)[0], a1 = ((const float4*)s0)[1];
            float4 b0 = ((const float4*)(s0 + Nn))[0], b1 = ((const float4*)(s0 + Nn))[1];
            const float av[8] = {a0.x, a0.y, a0.z, a0.w, a1.x, a1.y, a1.z, a1.w};
            const float bv[8] = {b0.x, b0.y, b0.z, b0.w, b1.x, b1.y, b1.z, b1.w};
            #pragma unroll
            for (int j = 0; j < 8; ++j) {
                const int n = kgN + j;
                kw[n * 64 + (kdp ^ (swz(n) << 2))] = packh2(av[j], bv[j]);
            }
            // ---- stage V tile: fp32 [kk][d] -> vb[d][kk-pair ^ sw4] ----
            const float* t0 = vbase + (size_t)(n0 + 2 * vkp) * Dd + vgD;
            float4 c0 = ((const float4*)t0)[0], c1 = ((const float4*)t0)[1];
            float4 d0 = ((const float4*)(t0 + Dd))[0], d1 = ((const float4*)(t0 + Dd))[1];
            const float cv[8] = {c0.x, c0.y, c0.z, c0.w, c1.x, c1.y, c1.z, c1.w};
            const float dv[8] = {d0.x, d0.y, d0.z, d0.w, d1.x, d1.y, d1.z, d1.w};
            #pragma unroll
            for (int j = 0; j < 8; ++j) {
                const int dd = vgD + j;
                vw[dd * 16 + (vkp ^ (sw4(dd) << 2))] = packh2(cv[j], dv[j]);
            }
        }
        __syncthreads();

        // ---- S^T[kk=32][q=16] = K' x Q^T : 2 kt chains x 4 chunks ----
        f32x4 accS[2];
        #pragma unroll
        for (int kt = 0; kt < 2; ++kt) {
            f32x4 s = f32x4{0.f, 0.f, 0.f, 0.f};
            const int row = kt * 16 + l15;       // kk (A-frag m)
            const int sw = swz(row) << 3;
            #pragma unroll
            for (int c = 0; c < 4; ++c) {
                f16x8 kf = *(const f16x8*)&kb[row * 128 + ((c * 32 + quad * 8) ^ sw)];
                s = __builtin_amdgcn_mfma_f32_16x16x32_f16(kf, qf[c], s, 0, 0, 0);
            }
            accS[kt] = s;
        }

        // ---- online softmax, per-lane row (q=l15), butterfly over quads ----
        float mx = fmaxf(fmaxf(fmaxf(accS[0][0], accS[0][1]), fmaxf(accS[0][2], accS[0][3])),
                         fmaxf(fmaxf(accS[1][0], accS[1][1]), fmaxf(accS[1][2], accS[1][3])));
        mx = fmaxf(mx, __shfl_xor(mx, 16, 64));
        mx = fmaxf(mx, __shfl_xor(mx, 32, 64));
        const float mn = fmaxf(m_i, mx);
        const float alpha = __expf(m_i - mn);
        m_i = mn;
        float local = 0.f;
        #pragma unroll
        for (int kt = 0; kt < 2; ++kt)
            #pragma unroll
            for (int r = 0; r < 4; ++r) {
                const float p = __expf(accS[kt][r] - mn);
                accS[kt][r] = p;
                local += p;
            }
        l_i = l_i * alpha + local;
        #pragma unroll
        for (int dt = 0; dt < 8; ++dt)
            #pragma unroll
            for (int r = 0; r < 4; ++r) accO[dt][r] *= alpha;

        // ---- P^T -> LDS [q][kk] (wave-private): 2 b64 writes, 1 b128 read ----
        #pragma unroll
        for (int kt = 0; kt < 2; ++kt) {
            uint2 pw;
            pw.x = packh2(accS[kt][0], accS[kt][1]);
            pw.y = packh2(accS[kt][2], accS[kt][3]);
            *(uint2*)(pl + l15 * PK + kt * 16 + quad * 4) = pw;
        }
        f16x8 pf = *(const f16x8*)&pl[l15 * PK + quad * 8];

        // ---- O^T += V' x P^T : 8 independent 1-chains, K=32 ----
        #pragma unroll
        for (int dt = 0; dt < 8; ++dt) {
            const int drow = dt * 16 + l15;      // dout (A-frag m)
            const int sv = sw4(drow) << 3;
            f16x8 vf = *(const f16x8*)&vb[drow * 32 + ((quad * 8) ^ sv)];
            accO[dt] = __builtin_amdgcn_mfma_f32_16x16x32_f16(vf, pf, accO[dt], 0, 0, 0);
        }
        __syncthreads();   // guard K/V/P before next stage
    }

    // ---- reduce l across quads (full butterfly -> uniform) ----
    float lr = l_i;
    lr += __shfl_xor(lr, 16, 64);
    lr += __shfl_xor(lr, 32, 64);

    // ---- merge the two key-halves via LDS overlay ----
    float* mergef = (float*)smem;                 // 8192 floats (K/V region, dead)
    float* mlf = (float*)(smem + 16384);          // ml[4][16][2] (P region, dead)
    if (g == 1) {
        #pragma unroll
        for (int dt = 0; dt < 8; ++dt) {
            const int gr = (dt * 4 + quad) ^ ((l15 & 7) << 2);   // granule swizzle
            float4 val;
            val.x = accO[dt][0]; val.y = accO[dt][1];
            val.z = accO[dt][2]; val.w = accO[dt][3];
            *(float4*)(mergef + w * 2048 + l15 * 128 + gr * 4) = val;
        }
        if (quad == 0) {
            mlf[w * 32 + l15 * 2]     = m_i;
            mlf[w * 32 + l15 * 2 + 1] = lr;
        }
    }
    __syncthreads();
    if (g == 0) {
        const float mB = mlf[w * 32 + l15 * 2];
        const float lB = mlf[w * 32 + l15 * 2 + 1];
        const float m  = fmaxf(m_i, mB);
        const float eA = __expf(m_i - m);
        const float eB = __expf(mB - m);
        const float inv = 1.f / (lr * eA + lB * eB);
        float* ob = og + (size_t)(b * Nn + q0 + w * 16 + l15) * Dd;
        #pragma unroll
        for (int dt = 0; dt < 8; ++dt) {
            const int gr = (dt * 4 + quad) ^ ((l15 & 7) << 2);
            float4 vB = *(const float4*)(mergef + w * 2048 + l15 * 128 + gr * 4);
            float4 val;
            val.x = (accO[dt][0] * eA + vB.x * eB) * inv;
            val.y = (accO[dt][1] * eA + vB.y * eB) * inv;
            val.z = (accO[dt][2] * eA + vB.z * eB) * inv;
            val.w = (accO[dt][3] * eA + vB.w * eB) * inv;
            *(float4*)(ob + dt * 16 + quad * 4) = val;
        }
    }
}

extern "C" void kernel_launch(void* const* d_in, const int* in_sizes, int n_in,
                              void* d_out, int out_size, void* d_ws, size_t ws_size,
                              hipStream_t stream) {
    const float* q = (const float*)d_in[0];
    const float* k = (const float*)d_in[1];
    const float* v = (const float*)d_in[2];
    float* o = (float*)d_out;
    (void)d_ws; (void)ws_size; (void)in_sizes; (void)n_in; (void)out_size;
    fattn_kernel<<<dim3(Bz * (Nn / BM)), dim3(512), 0, stream>>>(q, k, v, o);
}